// Round 2
// baseline (296.439 us; speedup 1.0000x reference)
//
#include <hip/hip_runtime.h>
#include <hip/hip_cooperative_groups.h>
#include <stdint.h>

namespace cg = cooperative_groups;
typedef unsigned long long u64;

#define BATCH 32
#define H 512
#define W 512
#define WPR 8
#define WORDS_IMG (H * WPR)
#define NPIX (H * W)

#define NSTRIP 8
#define OWN 64
#define T_PAIRS 16
#define HALO 32            // 2*T_PAIRS
#define RL 128             // OWN + 2*HALO
#define WP 9               // padded LDS row stride (u64 words)
#define MAXPHASE 64

// ---------------- bit-sliced Zhang-Suen sub-iteration (2 rows/thread) -------
__device__ __forceinline__ void fulladd(u64 a, u64 b, u64 c, u64& s, u64& cy) {
    u64 t = a ^ b;
    s = t ^ c;
    cy = (a & b) | (t & c);
}

template<bool FIRST>
__device__ __forceinline__ u64 subiter2(const u64* __restrict__ src,
                                        u64* __restrict__ dst,
                                        int rg, int wc) {
    const int r = 2 * rg;
    u64 C[4], L[4], R[4];
    #pragma unroll
    for (int i = 0; i < 4; ++i) {
        int rr = r - 1 + i;
        bool v = (rr >= 0) && (rr < RL);
        const u64* row = src + rr * WP;
        C[i] = v ? row[wc] : 0ull;
        L[i] = (v && wc > 0) ? row[wc - 1] : 0ull;
        R[i] = (v && wc < 7) ? row[wc + 1] : 0ull;
    }
    u64 Wst[4], Est[4];
    #pragma unroll
    for (int i = 0; i < 4; ++i) {
        Wst[i] = (C[i] << 1) | (L[i] >> 63);
        Est[i] = (C[i] >> 1) | (R[i] << 63);
    }
    u64 diff = 0;
    #pragma unroll
    for (int k = 0; k < 2; ++k) {
        u64 P2 = C[k],     P9 = Wst[k],     P3 = Est[k];
        u64 cC = C[k + 1], P8 = Wst[k + 1], P4 = Est[k + 1];
        u64 P6 = C[k + 2], P7 = Wst[k + 2], P5 = Est[k + 2];

        u64 s1, c1, s2, c2, s3, c3, ts, tc, us, uc;
        fulladd(P2, P3, P4, s1, c1);
        fulladd(P5, P6, P7, s2, c2);
        s3 = P8 ^ P9; c3 = P8 & P9;
        fulladd(s1, s2, s3, ts, tc);
        fulladd(c1, c2, c3, us, uc);
        u64 vs = us ^ tc, vc = us & tc;
        u64 w4 = uc ^ vc, w8 = uc & vc;
        u64 condB = (vs | w4 | w8) & ~(w8 | (w4 & vs & ts));

        u64 seen, multi, t;
        t = ~P2 & P3; seen = t;  multi = 0;
        t = ~P3 & P4; multi |= seen & t; seen |= t;
        t = ~P4 & P5; multi |= seen & t; seen |= t;
        t = ~P5 & P6; multi |= seen & t; seen |= t;
        t = ~P6 & P7; multi |= seen & t; seen |= t;
        t = ~P7 & P8; multi |= seen & t; seen |= t;
        t = ~P8 & P9; multi |= seen & t; seen |= t;
        t = ~P9 & P2; multi |= seen & t; seen |= t;
        u64 ex1 = seen & ~multi;

        u64 cond = FIRST ? (~(P2 & P4 & P6) & ~(P4 & P6 & P8))
                         : (~(P2 & P4 & P8) & ~(P2 & P6 & P8));

        u64 rem = cC & condB & ex1 & cond;
        u64 nw = cC & ~rem;
        dst[(r + k) * WP + wc] = nw;
        diff |= nw ^ cC;
    }
    return diff;
}

__device__ __forceinline__ void dilate2(const u64* __restrict__ src,
                                        u64* __restrict__ dst,
                                        int rg, int wc) {
    const int r = 2 * rg;
    u64 C[4];
    #pragma unroll
    for (int i = 0; i < 4; ++i) {
        int rr = r - 1 + i;
        C[i] = (rr >= 0 && rr < RL) ? src[rr * WP + wc] : 0ull;
    }
    #pragma unroll
    for (int k = 0; k < 2; ++k) {
        int rr = r + k;
        u64 lw = (wc > 0) ? src[rr * WP + wc - 1] : 0ull;
        u64 rw = (wc < 7) ? src[rr * WP + wc + 1] : 0ull;
        u64 c = C[k + 1];
        u64 west = (c << 1) | (lw >> 63);
        u64 east = (c >> 1) | (rw << 63);
        dst[rr * WP + wc] = c | C[k] | C[k + 2] | west | east;
    }
}

// --------------- cooperative: pack + fixpoint + dilate + reduce -------------
__global__ void __launch_bounds__(512, 1)
skel_coop(const int* __restrict__ y, const float* __restrict__ x,
          u64* __restrict__ gA, u64* __restrict__ gB,
          int* __restrict__ flags, int* __restrict__ gt,
          float* __restrict__ partial)
{
    cg::grid_group grid = cg::this_grid();
    __shared__ u64 A[RL * WP];
    __shared__ u64 Bf[RL * WP];
    __shared__ int s_flag;
    __shared__ int s_gt;
    __shared__ float s_red[8];

    const int tid  = threadIdx.x;
    const int lane = tid & 63;
    const int wv   = tid >> 6;
    const int blk  = blockIdx.x;
    const int b    = blk >> 3;
    const int s    = blk & 7;
    const int row0 = s * OWN;

    const int*   yb  = y + (size_t)b * NPIX;
    const float* xb  = x + (size_t)b * NPIX;
    u64* gAb = gA + (size_t)b * WORDS_IMG;
    u64* gBb = gB + (size_t)b * WORDS_IMG;

    const int rg = tid >> 3;   // 0..63 -> rows 2rg, 2rg+1
    const int wc = tid & 7;

    // ---- pack owned rows via 64-lane ballot; write LDS + gA ----
    for (int w = wv * 64; w < wv * 64 + 64; ++w) {
        int r = w >> 3, c = w & 7;
        int v = yb[(row0 + r) * W + c * 64 + lane];
        u64 m = __ballot(v != 0);
        if (lane == 0) {
            A[(HALO + r) * WP + c] = m;
            gAb[(row0 + r) * WPR + c] = m;
        }
    }
    __threadfence();
    grid.sync();
    __threadfence();

    // ---- load halos (32 rows top + 32 bottom) ----
    {
        int side = tid >> 8;
        int idx  = tid & 255;
        int r_l  = idx >> 3, c = idx & 7;
        int lrow = side ? (HALO + OWN + r_l) : r_l;
        int grow = row0 - HALO + lrow;
        u64 v = 0;
        if (grow >= 0 && grow < H) v = gAb[grow * WPR + c];
        A[lrow * WP + c] = v;
    }
    __syncthreads();

    // ---- fixpoint phases ----
    int cur = 0;            // 0 => gA current, 1 => gB current
    bool converged = false;
    for (int phase = 0; phase < MAXPHASE && !converged; ++phase) {
        u64 mydiff = 0;
        #pragma unroll 1
        for (int pr = 0; pr < T_PAIRS; ++pr) {
            u64 d1 = subiter2<true>(A, Bf, rg, wc);
            __syncthreads();
            u64 d2 = subiter2<false>(Bf, A, rg, wc);
            if (pr == T_PAIRS - 1) mydiff = d1 | d2;
            __syncthreads();
        }
        if (rg < 16 || rg >= 48) mydiff = 0;   // owned rows only

        // write owned rows to the other global buffer
        u64* dst = cur ? gAb : gBb;
        if (rg >= 16 && rg < 48) {
            int r = 2 * rg - HALO;
            dst[(row0 + r) * WPR + wc]     = A[(2 * rg) * WP + wc];
            dst[(row0 + r + 1) * WPR + wc] = A[(2 * rg + 1) * WP + wc];
        }
        if (tid == 0) s_flag = 0;
        __syncthreads();
        if (mydiff) atomicOr(&s_flag, 1);
        __syncthreads();
        if (tid == 0 && s_flag) atomicOr(&flags[phase], 1);
        __threadfence();
        grid.sync();
        __threadfence();
        if (tid == 0) s_flag = atomicOr(&flags[phase], 0);
        __syncthreads();
        converged = (s_flag == 0);
        cur ^= 1;
        if (!converged) {
            const u64* srcg = cur ? gBb : gAb;
            int side = tid >> 8;
            int idx  = tid & 255;
            int r_l  = idx >> 3, c = idx & 7;
            int lrow = side ? (HALO + OWN + r_l) : r_l;
            int grow = row0 - HALO + lrow;
            u64 v = 0;
            if (grow >= 0 && grow < H) v = srcg[grow * WPR + c];
            A[lrow * WP + c] = v;
            __syncthreads();
        }
    }

    // ---- reload +-2 halo rows, dilate twice ----
    {
        const u64* srcg = cur ? gBb : gAb;
        if (tid < 32) {
            int side = tid >> 4;
            int idx  = tid & 15;
            int r_l  = idx >> 3, c = idx & 7;
            int lrow = side ? (HALO + OWN + r_l) : (HALO - 2 + r_l);
            int grow = row0 - HALO + lrow;
            u64 v = 0;
            if (grow >= 0 && grow < H) v = srcg[grow * WPR + c];
            A[lrow * WP + c] = v;
        }
    }
    __syncthreads();
    dilate2(A, Bf, rg, wc);
    __syncthreads();
    dilate2(Bf, A, rg, wc);
    __syncthreads();

    // ---- gt popcount (int atomics, deterministic) ----
    if (tid == 0) s_gt = 0;
    __syncthreads();
    if (rg >= 16 && rg < 48) {
        int pc = __popcll(A[(2 * rg) * WP + wc]) + __popcll(A[(2 * rg + 1) * WP + wc]);
        atomicAdd(&s_gt, pc);
    }
    __syncthreads();
    if (tid == 0) atomicAdd(&gt[b], s_gt);

    // ---- intersection with x over owned strip ----
    float sum = 0.0f;
    const float* xs = xb + (size_t)row0 * W;
    #pragma unroll 4
    for (int i = 0; i < OWN; ++i) {
        u64 word = A[(HALO + i) * WP + wv];
        if ((word >> lane) & 1ull) sum += xs[i * W + tid];
    }
    for (int off = 32; off >= 1; off >>= 1) sum += __shfl_down(sum, off, 64);
    if (lane == 0) s_red[wv] = sum;
    __syncthreads();
    if (tid == 0) {
        float t = 0.0f;
        #pragma unroll
        for (int k = 0; k < 8; ++k) t += s_red[k];
        partial[blk] = t;
    }
}

// --------------- final: recall per image, mean, negate ----------------------
__global__ __launch_bounds__(64) void final_kernel(const float* __restrict__ partial,
                                                   const int* __restrict__ gt,
                                                   float* __restrict__ out) {
    __shared__ float rec[32];
    int t = threadIdx.x;
    if (t < 32) {
        float s = 0.0f;
        for (int j = 0; j < 8; ++j) s += partial[t * 8 + j];
        rec[t] = (s + 1.0f) / ((float)gt[t] + 1.0f);
    }
    __syncthreads();
    if (t == 0) {
        float s = 0.0f;
        for (int i = 0; i < 32; ++i) s += rec[i];
        out[0] = -(s / 32.0f);
    }
}

extern "C" void kernel_launch(void* const* d_in, const int* in_sizes, int n_in,
                              void* d_out, int out_size, void* d_ws, size_t ws_size,
                              hipStream_t stream) {
    const float* x = (const float*)d_in[0];
    const int*   y = (const int*)d_in[1];
    float* out = (float*)d_out;

    char* ws = (char*)d_ws;
    u64* gA = (u64*)ws;
    u64* gB = (u64*)(ws + (size_t)BATCH * WORDS_IMG * 8);
    int* flags = (int*)(ws + 2 * (size_t)BATCH * WORDS_IMG * 8);
    int* gt = flags + MAXPHASE;
    float* partial = (float*)(gt + BATCH);

    hipMemsetAsync(flags, 0, (MAXPHASE + BATCH) * sizeof(int), stream);

    void* args[] = {(void*)&y, (void*)&x, (void*)&gA, (void*)&gB,
                    (void*)&flags, (void*)&gt, (void*)&partial};
    hipLaunchCooperativeKernel((void*)skel_coop, dim3(BATCH * NSTRIP), dim3(512),
                               args, 0, stream);

    final_kernel<<<1, 64, 0, stream>>>(partial, gt, out);
}

// Round 3
// 78.575 us; speedup vs baseline: 3.7727x; 3.7727x over previous
//
#include <hip/hip_runtime.h>
#include <stdint.h>

typedef unsigned long long u64;

#define BATCH 32
#define H 512
#define W 512
#define WPR 8                     // u64 words per row
#define WORDS_IMG (H * WPR)       // 4096
#define NPIX (H * W)

#define NSTRIP 8
#define OWN 64
#define HALO 32
#define RL 128                    // OWN + 2*HALO
#define WP 9                      // padded LDS row stride
#define PAIRS 16                  // pairs per strip dispatch (= HALO/2)
#define NPHASE 4                  // strip dispatches (64 pairs capacity)

// ---------------- pack: y(int32 0/1) -> bitboards via 64-bit ballot ----------
__global__ __launch_bounds__(256) void pack_kernel(const int* __restrict__ y,
                                                   u64* __restrict__ words) {
    int gtid = blockIdx.x * blockDim.x + threadIdx.x;
    int lane = gtid & 63;
    int wave = gtid >> 6;
    int nwaves = (gridDim.x * blockDim.x) >> 6;
    for (int w = wave; w < BATCH * WORDS_IMG; w += nwaves) {
        int v = y[(size_t)w * 64 + lane];
        u64 m = __ballot(v != 0);
        if (lane == 0) words[w] = m;
    }
}

// ---------------- bit-sliced Zhang-Suen sub-iteration helpers ----------------
__device__ __forceinline__ void fulladd(u64 a, u64 b, u64 c, u64& s, u64& cy) {
    u64 t = a ^ b;
    s = t ^ c;
    cy = (a & b) | (t & c);
}

// strip version: RL rows, stride WP, 2 rows per thread
template<bool FIRST>
__device__ __forceinline__ u64 subiter2(const u64* __restrict__ src,
                                        u64* __restrict__ dst,
                                        int rg, int wc) {
    const int r = 2 * rg;
    u64 C[4], L[4], R[4];
    #pragma unroll
    for (int i = 0; i < 4; ++i) {
        int rr = r - 1 + i;
        bool v = (rr >= 0) && (rr < RL);
        const u64* row = src + rr * WP;
        C[i] = v ? row[wc] : 0ull;
        L[i] = (v && wc > 0) ? row[wc - 1] : 0ull;
        R[i] = (v && wc < 7) ? row[wc + 1] : 0ull;
    }
    u64 Wst[4], Est[4];
    #pragma unroll
    for (int i = 0; i < 4; ++i) {
        Wst[i] = (C[i] << 1) | (L[i] >> 63);
        Est[i] = (C[i] >> 1) | (R[i] << 63);
    }
    u64 diff = 0;
    #pragma unroll
    for (int k = 0; k < 2; ++k) {
        u64 P2 = C[k],     P9 = Wst[k],     P3 = Est[k];
        u64 cC = C[k + 1], P8 = Wst[k + 1], P4 = Est[k + 1];
        u64 P6 = C[k + 2], P7 = Wst[k + 2], P5 = Est[k + 2];

        u64 s1, c1, s2, c2, s3, c3, ts, tc, us, uc;
        fulladd(P2, P3, P4, s1, c1);
        fulladd(P5, P6, P7, s2, c2);
        s3 = P8 ^ P9; c3 = P8 & P9;
        fulladd(s1, s2, s3, ts, tc);
        fulladd(c1, c2, c3, us, uc);
        u64 vs = us ^ tc, vc = us & tc;
        u64 w4 = uc ^ vc, w8 = uc & vc;
        u64 condB = (vs | w4 | w8) & ~(w8 | (w4 & vs & ts));

        u64 seen, multi, t;
        t = ~P2 & P3; seen = t;  multi = 0;
        t = ~P3 & P4; multi |= seen & t; seen |= t;
        t = ~P4 & P5; multi |= seen & t; seen |= t;
        t = ~P5 & P6; multi |= seen & t; seen |= t;
        t = ~P6 & P7; multi |= seen & t; seen |= t;
        t = ~P7 & P8; multi |= seen & t; seen |= t;
        t = ~P8 & P9; multi |= seen & t; seen |= t;
        t = ~P9 & P2; multi |= seen & t; seen |= t;
        u64 ex1 = seen & ~multi;

        u64 cond = FIRST ? (~(P2 & P4 & P6) & ~(P4 & P6 & P8))
                         : (~(P2 & P4 & P8) & ~(P2 & P6 & P8));

        u64 rem = cC & condB & ex1 & cond;
        u64 nw = cC & ~rem;
        dst[(r + k) * WP + wc] = nw;
        diff |= nw ^ cC;
    }
    return diff;
}

// full-image version for the fallback kernel (stride WPR, 8 rows/thread)
template<bool FIRST>
__device__ __forceinline__ void compute_sub_full(const u64* img, int wc, int r0,
                                                 u64 nw[8], u64& diff) {
    u64 C[10], L[10], R[10];
    #pragma unroll
    for (int i = 0; i < 10; ++i) {
        int rr = r0 - 1 + i;
        bool valid = (rr >= 0) && (rr < H);
        C[i] = valid ? img[rr * WPR + wc] : 0ull;
        L[i] = (valid && wc > 0) ? img[rr * WPR + wc - 1] : 0ull;
        R[i] = (valid && wc < WPR - 1) ? img[rr * WPR + wc + 1] : 0ull;
    }
    #pragma unroll
    for (int k = 0; k < 8; ++k) {
        u64 P2 = C[k];
        u64 P9 = (C[k]   << 1) | (L[k]   >> 63);
        u64 P3 = (C[k]   >> 1) | (R[k]   << 63);
        u64 cC = C[k+1];
        u64 P8 = (C[k+1] << 1) | (L[k+1] >> 63);
        u64 P4 = (C[k+1] >> 1) | (R[k+1] << 63);
        u64 P6 = C[k+2];
        u64 P7 = (C[k+2] << 1) | (L[k+2] >> 63);
        u64 P5 = (C[k+2] >> 1) | (R[k+2] << 63);

        u64 s1, c1, s2, c2, s3, c3, ts, tc, us, uc;
        fulladd(P2, P3, P4, s1, c1);
        fulladd(P5, P6, P7, s2, c2);
        s3 = P8 ^ P9; c3 = P8 & P9;
        fulladd(s1, s2, s3, ts, tc);
        fulladd(c1, c2, c3, us, uc);
        u64 vs = us ^ tc, vc = us & tc;
        u64 w4 = uc ^ vc, w8 = uc & vc;
        u64 condB = (vs | w4 | w8) & ~(w8 | (w4 & vs & ts));

        u64 seen, multi, t;
        t = ~P2 & P3; seen = t;  multi = 0;
        t = ~P3 & P4; multi |= seen & t; seen |= t;
        t = ~P4 & P5; multi |= seen & t; seen |= t;
        t = ~P5 & P6; multi |= seen & t; seen |= t;
        t = ~P6 & P7; multi |= seen & t; seen |= t;
        t = ~P7 & P8; multi |= seen & t; seen |= t;
        t = ~P8 & P9; multi |= seen & t; seen |= t;
        t = ~P9 & P2; multi |= seen & t; seen |= t;
        u64 ex1 = seen & ~multi;

        u64 cond = FIRST ? (~(P2 & P4 & P6) & ~(P4 & P6 & P8))
                         : (~(P2 & P4 & P8) & ~(P2 & P6 & P8));

        u64 rem = cC & condB & ex1 & cond;
        nw[k] = cC & ~rem;
        diff |= nw[k] ^ cC;
    }
}

// --------------- strip dispatch: up to PAIRS pairs, halo-redundant ----------
__global__ __launch_bounds__(512)
void strip_iter(const u64* __restrict__ gsrc, u64* __restrict__ gdst,
                int* __restrict__ flags, int phase) {
    if (phase > 0 && flags[phase - 1] == 0) return;   // already converged

    __shared__ u64 A[RL * WP];
    __shared__ u64 Bf[RL * WP];
    __shared__ int s_any[2];

    const int tid = threadIdx.x;
    const int blk = blockIdx.x;
    const int b = blk >> 3;
    const int s = blk & 7;
    const int row0 = s * OWN;
    const int lane = tid & 63;
    const u64* src = gsrc + (size_t)b * WORDS_IMG;
    u64* dst = gdst + (size_t)b * WORDS_IMG;

    // load 128 rows (own + halo), zero outside image
    #pragma unroll
    for (int i = 0; i < 2; ++i) {
        int t = tid + i * 512;
        int lrow = t >> 3, c = t & 7;
        int grow = row0 - HALO + lrow;
        u64 v = 0;
        if (grow >= 0 && grow < H) v = src[grow * WPR + c];
        A[lrow * WP + c] = v;
    }
    if (tid < 2) s_any[tid] = 0;
    __syncthreads();

    const int rg = tid >> 3;
    const int wc = tid & 7;
    u64 lastown = 0;
    for (int pr = 0; pr < PAIRS; ++pr) {
        u64 d1 = subiter2<true>(A, Bf, rg, wc);
        __syncthreads();
        u64 d2 = subiter2<false>(Bf, A, rg, wc);
        u64 d = d1 | d2;
        lastown = (rg >= 16 && rg < 48) ? d : 0;
        int p = pr & 1;
        u64 bal = __ballot(d != 0);
        if (lane == 0 && bal) atomicOr(&s_any[p], 1);
        __syncthreads();                  // A visible + s_any settled
        int any = s_any[p];
        if (tid == 0) s_any[p ^ 1] = 0;   // ordered before next atomicOr by next barrier
        if (!any) break;                  // strip is a local fixpoint -> rest identity
    }

    // write owned rows
    if (rg >= 16 && rg < 48) {
        int r = 2 * rg;
        dst[(row0 + r - HALO) * WPR + wc]     = A[r * WP + wc];
        dst[(row0 + r - HALO + 1) * WPR + wc] = A[(r + 1) * WP + wc];
    }
    // flags[phase] |= "this dispatch's final pair changed an owned row"
    u64 bal = __ballot(lastown != 0);
    if (lane == 0 && bal) atomicOr(&flags[phase], 1);
}

// --------------- fallback: exact fixpoint if 64 pairs weren't enough --------
__global__ __launch_bounds__(512)
void fallback_kernel(u64* __restrict__ gA, const int* __restrict__ flags) {
    if (flags[NPHASE - 1] == 0) return;   // converged within strip dispatches

    __shared__ u64 img[WORDS_IMG];        // 32 KB
    __shared__ int s_changed;
    const int b = blockIdx.x;
    const int tid = threadIdx.x;
    const int wc = tid & 7;
    const int r0 = (tid >> 3) * 8;
    u64* gimg = gA + (size_t)b * WORDS_IMG;

    #pragma unroll
    for (int k = 0; k < 8; ++k)
        img[(r0 + k) * WPR + wc] = gimg[(r0 + k) * WPR + wc];
    if (tid == 0) s_changed = 0;
    __syncthreads();

    bool changed = true;
    for (int it = 0; it < 4096 && changed; ++it) {
        u64 diff = 0;
        u64 nw[8];
        compute_sub_full<true>(img, wc, r0, nw, diff);
        __syncthreads();
        #pragma unroll
        for (int k = 0; k < 8; ++k) img[(r0 + k) * WPR + wc] = nw[k];
        __syncthreads();
        compute_sub_full<false>(img, wc, r0, nw, diff);
        __syncthreads();
        #pragma unroll
        for (int k = 0; k < 8; ++k) img[(r0 + k) * WPR + wc] = nw[k];
        if (diff) atomicOr(&s_changed, 1);
        __syncthreads();
        changed = (s_changed != 0);
        __syncthreads();
        if (tid == 0) s_changed = 0;
    }

    #pragma unroll
    for (int k = 0; k < 8; ++k)
        gimg[(r0 + k) * WPR + wc] = img[(r0 + k) * WPR + wc];
}

// --------------- epilogue: dilate x2 + gt popcount + intersection -----------
#define ERL 68                    // OWN + 4 halo rows

__global__ __launch_bounds__(512)
void epilogue_kernel(const u64* __restrict__ gA, const u64* __restrict__ gB,
                     const int* __restrict__ flags, const float* __restrict__ x,
                     float* __restrict__ partial, int* __restrict__ partial_gt) {
    // which buffer holds the fixpoint: nRan strip dispatches ran; odd -> gB
    int nRan = 1 + (flags[0] ? 1 : 0) + (flags[1] ? 1 : 0) + (flags[2] ? 1 : 0);
    const u64* cur = (nRan & 1) ? gB : gA;

    __shared__ u64 D[ERL * WP];
    __shared__ u64 E[ERL * WP];
    __shared__ float s_red[8];
    __shared__ int s_pc[8];

    const int tid = threadIdx.x;
    const int blk = blockIdx.x;
    const int b = blk >> 3;
    const int s = blk & 7;
    const int row0 = s * OWN;
    const int lane = tid & 63;
    const int wv = tid >> 6;
    const u64* src = cur + (size_t)b * WORDS_IMG;
    const float* xb = x + (size_t)b * NPIX;

    // load rows row0-2 .. row0+65
    for (int t = tid; t < ERL * 8; t += 512) {
        int lrow = t >> 3, c = t & 7;
        int grow = row0 - 2 + lrow;
        u64 v = 0;
        if (grow >= 0 && grow < H) v = src[grow * WPR + c];
        D[lrow * WP + c] = v;
    }
    __syncthreads();

    // dilate pass 1: D -> E (rows outside image forced to 0 = reference pad)
    for (int t = tid; t < ERL * 8; t += 512) {
        int l = t >> 3, c = t & 7;
        int grow = row0 - 2 + l;
        u64 v = 0;
        if (grow >= 0 && grow < H) {
            u64 cc = D[l * WP + c];
            u64 up = (l > 0)       ? D[(l - 1) * WP + c] : 0ull;
            u64 dn = (l < ERL - 1) ? D[(l + 1) * WP + c] : 0ull;
            u64 lw = (c > 0) ? D[l * WP + c - 1] : 0ull;
            u64 rw = (c < 7) ? D[l * WP + c + 1] : 0ull;
            v = cc | up | dn | ((cc << 1) | (lw >> 63)) | ((cc >> 1) | (rw << 63));
        }
        E[l * WP + c] = v;
    }
    __syncthreads();
    // dilate pass 2: E -> D
    for (int t = tid; t < ERL * 8; t += 512) {
        int l = t >> 3, c = t & 7;
        int grow = row0 - 2 + l;
        u64 v = 0;
        if (grow >= 0 && grow < H) {
            u64 cc = E[l * WP + c];
            u64 up = (l > 0)       ? E[(l - 1) * WP + c] : 0ull;
            u64 dn = (l < ERL - 1) ? E[(l + 1) * WP + c] : 0ull;
            u64 lw = (c > 0) ? E[l * WP + c - 1] : 0ull;
            u64 rw = (c < 7) ? E[l * WP + c + 1] : 0ull;
            v = cc | up | dn | ((cc << 1) | (lw >> 63)) | ((cc >> 1) | (rw << 63));
        }
        D[l * WP + c] = v;
    }
    __syncthreads();

    // gt popcount over owned rows (LDS rows 2..65); one word per thread
    int pc;
    {
        int l = 2 + (tid >> 3), c = tid & 7;
        pc = __popcll(D[l * WP + c]);
    }
    for (int off = 32; off >= 1; off >>= 1) pc += __shfl_down(pc, off, 64);
    if (lane == 0) s_pc[wv] = pc;

    // intersection with x over owned rows; thread owns column tid
    float sum = 0.0f;
    for (int i = 0; i < OWN; ++i) {
        u64 word = D[(2 + i) * WP + wv];
        if (word) {   // wave-uniform skip
            float m = (float)((word >> lane) & 1ull);
            sum = fmaf(m, xb[(size_t)(row0 + i) * W + tid], sum);
        }
    }
    for (int off = 32; off >= 1; off >>= 1) sum += __shfl_down(sum, off, 64);
    if (lane == 0) s_red[wv] = sum;
    __syncthreads();
    if (tid == 0) {
        float fs = 0.0f;
        int is = 0;
        #pragma unroll
        for (int k = 0; k < 8; ++k) { fs += s_red[k]; is += s_pc[k]; }
        partial[blk] = fs;
        partial_gt[blk] = is;
    }
}

// --------------- final: recall per image, mean, negate ----------------------
__global__ __launch_bounds__(64)
void final_kernel(const float* __restrict__ partial,
                  const int* __restrict__ partial_gt,
                  float* __restrict__ out) {
    __shared__ float rec[32];
    int t = threadIdx.x;
    if (t < 32) {
        float inter = 0.0f;
        int g = 0;
        for (int j = 0; j < 8; ++j) {
            inter += partial[t * 8 + j];
            g += partial_gt[t * 8 + j];
        }
        rec[t] = (inter + 1.0f) / ((float)g + 1.0f);
    }
    __syncthreads();
    if (t == 0) {
        float s = 0.0f;
        for (int i = 0; i < 32; ++i) s += rec[i];
        out[0] = -(s / 32.0f);
    }
}

extern "C" void kernel_launch(void* const* d_in, const int* in_sizes, int n_in,
                              void* d_out, int out_size, void* d_ws, size_t ws_size,
                              hipStream_t stream) {
    const float* x = (const float*)d_in[0];
    const int*   y = (const int*)d_in[1];
    float* out = (float*)d_out;

    char* ws = (char*)d_ws;
    u64* gA = (u64*)ws;
    u64* gB = (u64*)(ws + (size_t)BATCH * WORDS_IMG * 8);
    int* flags = (int*)(ws + 2 * (size_t)BATCH * WORDS_IMG * 8);
    float* partial = (float*)(flags + NPHASE);
    int* partial_gt = (int*)(partial + BATCH * NSTRIP);

    hipMemsetAsync(flags, 0, NPHASE * sizeof(int), stream);
    pack_kernel<<<512, 256, 0, stream>>>(y, gA);
    for (int p = 0; p < NPHASE; ++p) {
        const u64* src = (p & 1) ? gB : gA;
        u64* dst = (p & 1) ? gA : gB;
        strip_iter<<<BATCH * NSTRIP, 512, 0, stream>>>(src, dst, flags, p);
    }
    fallback_kernel<<<BATCH, 512, 0, stream>>>(gA, flags);
    epilogue_kernel<<<BATCH * NSTRIP, 512, 0, stream>>>(gA, gB, flags, x,
                                                        partial, partial_gt);
    final_kernel<<<1, 64, 0, stream>>>(partial, partial_gt, out);
}

// Round 4
// 63.300 us; speedup vs baseline: 4.6831x; 1.2413x over previous
//
#include <hip/hip_runtime.h>
#include <stdint.h>

typedef unsigned long long u64;
typedef unsigned int u32;

#define BATCH 32
#define H 512
#define W 512
#define WPR 8                     // u64 words per row
#define WORDS_IMG (H * WPR)       // 4096
#define NPIX (H * W)

#define NSTRIP 8
#define OWN 64
#define HALO 32
#define RL 128                    // OWN + 2*HALO
#define WP 9                      // padded LDS row stride
#define PAIRS 16                  // pairs per strip dispatch (= HALO/2)
#define NPHASE 4                  // strip dispatches (64 pairs capacity)
#define ERL 68                    // OWN + 2+2 halo rows for double dilation

// ---------------- pack: y(int32 0/1) -> bitboards via 64-bit ballot ----------
// also zeroes flags + gt (replaces the 40us fillBuffer dispatch)
__global__ __launch_bounds__(256) void pack_kernel(const int* __restrict__ y,
                                                   u64* __restrict__ words,
                                                   int* __restrict__ flags,
                                                   int* __restrict__ gt) {
    if (blockIdx.x == 0) {
        if (threadIdx.x < NPHASE) flags[threadIdx.x] = 0;
        if (threadIdx.x >= 64 && threadIdx.x < 64 + BATCH) gt[threadIdx.x - 64] = 0;
    }
    int gtid = blockIdx.x * blockDim.x + threadIdx.x;
    int lane = gtid & 63;
    int wave = gtid >> 6;
    int nwaves = (gridDim.x * blockDim.x) >> 6;
    for (int w = wave; w < BATCH * WORDS_IMG; w += nwaves) {
        int v = y[(size_t)w * 64 + lane];
        u64 m = __ballot(v != 0);
        if (lane == 0) words[w] = m;
    }
}

// ---------------- bit-sliced Zhang-Suen sub-iteration helpers ----------------
__device__ __forceinline__ void fulladd(u64 a, u64 b, u64 c, u64& s, u64& cy) {
    u64 t = a ^ b;
    s = t ^ c;
    cy = (a & b) | (t & c);
}

// strip version: RL rows, stride WP, 2 rows per thread
template<bool FIRST>
__device__ __forceinline__ u64 subiter2(const u64* __restrict__ src,
                                        u64* __restrict__ dst,
                                        int rg, int wc) {
    const int r = 2 * rg;
    u64 C[4], L[4], R[4];
    #pragma unroll
    for (int i = 0; i < 4; ++i) {
        int rr = r - 1 + i;
        bool v = (rr >= 0) && (rr < RL);
        const u64* row = src + rr * WP;
        C[i] = v ? row[wc] : 0ull;
        L[i] = (v && wc > 0) ? row[wc - 1] : 0ull;
        R[i] = (v && wc < 7) ? row[wc + 1] : 0ull;
    }
    u64 Wst[4], Est[4];
    #pragma unroll
    for (int i = 0; i < 4; ++i) {
        Wst[i] = (C[i] << 1) | (L[i] >> 63);
        Est[i] = (C[i] >> 1) | (R[i] << 63);
    }
    u64 diff = 0;
    #pragma unroll
    for (int k = 0; k < 2; ++k) {
        u64 P2 = C[k],     P9 = Wst[k],     P3 = Est[k];
        u64 cC = C[k + 1], P8 = Wst[k + 1], P4 = Est[k + 1];
        u64 P6 = C[k + 2], P7 = Wst[k + 2], P5 = Est[k + 2];

        u64 s1, c1, s2, c2, s3, c3, ts, tc, us, uc;
        fulladd(P2, P3, P4, s1, c1);
        fulladd(P5, P6, P7, s2, c2);
        s3 = P8 ^ P9; c3 = P8 & P9;
        fulladd(s1, s2, s3, ts, tc);
        fulladd(c1, c2, c3, us, uc);
        u64 vs = us ^ tc, vc = us & tc;
        u64 w4 = uc ^ vc, w8 = uc & vc;
        u64 condB = (vs | w4 | w8) & ~(w8 | (w4 & vs & ts));

        u64 seen, multi, t;
        t = ~P2 & P3; seen = t;  multi = 0;
        t = ~P3 & P4; multi |= seen & t; seen |= t;
        t = ~P4 & P5; multi |= seen & t; seen |= t;
        t = ~P5 & P6; multi |= seen & t; seen |= t;
        t = ~P6 & P7; multi |= seen & t; seen |= t;
        t = ~P7 & P8; multi |= seen & t; seen |= t;
        t = ~P8 & P9; multi |= seen & t; seen |= t;
        t = ~P9 & P2; multi |= seen & t; seen |= t;
        u64 ex1 = seen & ~multi;

        u64 cond = FIRST ? (~(P2 & P4 & P6) & ~(P4 & P6 & P8))
                         : (~(P2 & P4 & P8) & ~(P2 & P6 & P8));

        u64 rem = cC & condB & ex1 & cond;
        u64 nw = cC & ~rem;
        dst[(r + k) * WP + wc] = nw;
        diff |= nw ^ cC;
    }
    return diff;
}

// full-image version for the fallback kernel (stride WPR, 8 rows/thread)
template<bool FIRST>
__device__ __forceinline__ void compute_sub_full(const u64* img, int wc, int r0,
                                                 u64 nw[8], u64& diff) {
    u64 C[10], L[10], R[10];
    #pragma unroll
    for (int i = 0; i < 10; ++i) {
        int rr = r0 - 1 + i;
        bool valid = (rr >= 0) && (rr < H);
        C[i] = valid ? img[rr * WPR + wc] : 0ull;
        L[i] = (valid && wc > 0) ? img[rr * WPR + wc - 1] : 0ull;
        R[i] = (valid && wc < WPR - 1) ? img[rr * WPR + wc + 1] : 0ull;
    }
    #pragma unroll
    for (int k = 0; k < 8; ++k) {
        u64 P2 = C[k];
        u64 P9 = (C[k]   << 1) | (L[k]   >> 63);
        u64 P3 = (C[k]   >> 1) | (R[k]   << 63);
        u64 cC = C[k+1];
        u64 P8 = (C[k+1] << 1) | (L[k+1] >> 63);
        u64 P4 = (C[k+1] >> 1) | (R[k+1] << 63);
        u64 P6 = C[k+2];
        u64 P7 = (C[k+2] << 1) | (L[k+2] >> 63);
        u64 P5 = (C[k+2] >> 1) | (R[k+2] << 63);

        u64 s1, c1, s2, c2, s3, c3, ts, tc, us, uc;
        fulladd(P2, P3, P4, s1, c1);
        fulladd(P5, P6, P7, s2, c2);
        s3 = P8 ^ P9; c3 = P8 & P9;
        fulladd(s1, s2, s3, ts, tc);
        fulladd(c1, c2, c3, us, uc);
        u64 vs = us ^ tc, vc = us & tc;
        u64 w4 = uc ^ vc, w8 = uc & vc;
        u64 condB = (vs | w4 | w8) & ~(w8 | (w4 & vs & ts));

        u64 seen, multi, t;
        t = ~P2 & P3; seen = t;  multi = 0;
        t = ~P3 & P4; multi |= seen & t; seen |= t;
        t = ~P4 & P5; multi |= seen & t; seen |= t;
        t = ~P5 & P6; multi |= seen & t; seen |= t;
        t = ~P6 & P7; multi |= seen & t; seen |= t;
        t = ~P7 & P8; multi |= seen & t; seen |= t;
        t = ~P8 & P9; multi |= seen & t; seen |= t;
        t = ~P9 & P2; multi |= seen & t; seen |= t;
        u64 ex1 = seen & ~multi;

        u64 cond = FIRST ? (~(P2 & P4 & P6) & ~(P4 & P6 & P8))
                         : (~(P2 & P4 & P8) & ~(P2 & P6 & P8));

        u64 rem = cC & condB & ex1 & cond;
        nw[k] = cC & ~rem;
        diff |= nw[k] ^ cC;
    }
}

// --------------- strip dispatch: up to PAIRS pairs, halo-redundant ----------
__global__ __launch_bounds__(512)
void strip_iter(const u64* __restrict__ gsrc, u64* __restrict__ gdst,
                int* __restrict__ flags, int phase) {
    if (phase > 0 && flags[phase - 1] == 0) return;   // already converged

    __shared__ u64 A[RL * WP];
    __shared__ u64 Bf[RL * WP];
    __shared__ int s_any[2];

    const int tid = threadIdx.x;
    const int blk = blockIdx.x;
    const int b = blk >> 3;
    const int s = blk & 7;
    const int row0 = s * OWN;
    const int lane = tid & 63;
    const u64* src = gsrc + (size_t)b * WORDS_IMG;
    u64* dst = gdst + (size_t)b * WORDS_IMG;

    // load 128 rows (own + halo), zero outside image
    #pragma unroll
    for (int i = 0; i < 2; ++i) {
        int t = tid + i * 512;
        int lrow = t >> 3, c = t & 7;
        int grow = row0 - HALO + lrow;
        u64 v = 0;
        if (grow >= 0 && grow < H) v = src[grow * WPR + c];
        A[lrow * WP + c] = v;
    }
    if (tid < 2) s_any[tid] = 0;
    __syncthreads();

    const int rg = tid >> 3;
    const int wc = tid & 7;
    u64 lastown = 0;
    for (int pr = 0; pr < PAIRS; ++pr) {
        u64 d1 = subiter2<true>(A, Bf, rg, wc);
        __syncthreads();
        u64 d2 = subiter2<false>(Bf, A, rg, wc);
        u64 d = d1 | d2;
        lastown = (rg >= 16 && rg < 48) ? d : 0;
        int p = pr & 1;
        u64 bal = __ballot(d != 0);
        if (lane == 0 && bal) atomicOr(&s_any[p], 1);
        __syncthreads();                  // A visible + s_any settled
        int any = s_any[p];
        if (tid == 0) s_any[p ^ 1] = 0;   // ordered before next atomicOr by next barrier
        if (!any) break;                  // strip is a local fixpoint -> rest identity
    }

    // write owned rows
    if (rg >= 16 && rg < 48) {
        int r = 2 * rg;
        dst[(row0 + r - HALO) * WPR + wc]     = A[r * WP + wc];
        dst[(row0 + r - HALO + 1) * WPR + wc] = A[(r + 1) * WP + wc];
    }
    // flags[phase] |= "this dispatch's final pair changed an owned row"
    u64 bal = __ballot(lastown != 0);
    if (lane == 0 && bal) atomicOr(&flags[phase], 1);
}

// --------------- fallback: exact fixpoint if 64 pairs weren't enough --------
__global__ __launch_bounds__(512)
void fallback_kernel(u64* __restrict__ gA, const int* __restrict__ flags) {
    if (flags[NPHASE - 1] == 0) return;   // converged within strip dispatches

    __shared__ u64 img[WORDS_IMG];        // 32 KB
    __shared__ int s_changed;
    const int b = blockIdx.x;
    const int tid = threadIdx.x;
    const int wc = tid & 7;
    const int r0 = (tid >> 3) * 8;
    u64* gimg = gA + (size_t)b * WORDS_IMG;

    #pragma unroll
    for (int k = 0; k < 8; ++k)
        img[(r0 + k) * WPR + wc] = gimg[(r0 + k) * WPR + wc];
    if (tid == 0) s_changed = 0;
    __syncthreads();

    bool changed = true;
    for (int it = 0; it < 4096 && changed; ++it) {
        u64 diff = 0;
        u64 nw[8];
        compute_sub_full<true>(img, wc, r0, nw, diff);
        __syncthreads();
        #pragma unroll
        for (int k = 0; k < 8; ++k) img[(r0 + k) * WPR + wc] = nw[k];
        __syncthreads();
        compute_sub_full<false>(img, wc, r0, nw, diff);
        __syncthreads();
        #pragma unroll
        for (int k = 0; k < 8; ++k) img[(r0 + k) * WPR + wc] = nw[k];
        if (diff) atomicOr(&s_changed, 1);
        __syncthreads();
        changed = (s_changed != 0);
        __syncthreads();
        if (tid == 0) s_changed = 0;
    }

    #pragma unroll
    for (int k = 0; k < 8; ++k)
        gimg[(r0 + k) * WPR + wc] = img[(r0 + k) * WPR + wc];
}

// --------------- dilate x2 + gt popcount (mask only, small) -----------------
__global__ __launch_bounds__(512)
void dilate_gt_kernel(const u64* __restrict__ gA, const u64* __restrict__ gB,
                      const int* __restrict__ flags, int* __restrict__ gt) {
    int nRan = 1 + (flags[0] ? 1 : 0) + (flags[1] ? 1 : 0) + (flags[2] ? 1 : 0);
    const u64* fixb = (nRan & 1) ? gB : gA;   // fixpoint buffer
    u64* dilb       = (nRan & 1) ? (u64*)gA : (u64*)gB;  // write dilated here

    __shared__ u64 D[ERL * WP];
    __shared__ u64 E[ERL * WP];
    __shared__ int s_pc[8];

    const int tid = threadIdx.x;
    const int blk = blockIdx.x;
    const int b = blk >> 3;
    const int s = blk & 7;
    const int row0 = s * OWN;
    const int lane = tid & 63;
    const int wv = tid >> 6;
    const u64* src = fixb + (size_t)b * WORDS_IMG;
    u64* dst = dilb + (size_t)b * WORDS_IMG;

    for (int t = tid; t < ERL * 8; t += 512) {
        int lrow = t >> 3, c = t & 7;
        int grow = row0 - 2 + lrow;
        u64 v = 0;
        if (grow >= 0 && grow < H) v = src[grow * WPR + c];
        D[lrow * WP + c] = v;
    }
    __syncthreads();

    for (int t = tid; t < ERL * 8; t += 512) {
        int l = t >> 3, c = t & 7;
        int grow = row0 - 2 + l;
        u64 v = 0;
        if (grow >= 0 && grow < H) {
            u64 cc = D[l * WP + c];
            u64 up = (l > 0)       ? D[(l - 1) * WP + c] : 0ull;
            u64 dn = (l < ERL - 1) ? D[(l + 1) * WP + c] : 0ull;
            u64 lw = (c > 0) ? D[l * WP + c - 1] : 0ull;
            u64 rw = (c < 7) ? D[l * WP + c + 1] : 0ull;
            v = cc | up | dn | ((cc << 1) | (lw >> 63)) | ((cc >> 1) | (rw << 63));
        }
        E[l * WP + c] = v;
    }
    __syncthreads();

    // second pass: compute only owned rows (LDS rows 2..65), one word/thread
    const int l = 2 + (tid >> 3);
    const int c = tid & 7;
    u64 cc = E[l * WP + c];
    u64 up = E[(l - 1) * WP + c];
    u64 dn = E[(l + 1) * WP + c];
    u64 lw = (c > 0) ? E[l * WP + c - 1] : 0ull;
    u64 rw = (c < 7) ? E[l * WP + c + 1] : 0ull;
    u64 v = cc | up | dn | ((cc << 1) | (lw >> 63)) | ((cc >> 1) | (rw << 63));
    dst[(row0 + (tid >> 3)) * WPR + c] = v;

    int pc = __popcll(v);
    for (int off = 32; off >= 1; off >>= 1) pc += __shfl_down(pc, off, 64);
    if (lane == 0) s_pc[wv] = pc;
    __syncthreads();
    if (tid == 0) {
        int t = 0;
        #pragma unroll
        for (int k = 0; k < 8; ++k) t += s_pc[k];
        atomicAdd(&gt[b], t);
    }
}

// --------------- intersection: pure streaming over x ------------------------
__global__ __launch_bounds__(256)
void inter_kernel(const float* __restrict__ x,
                  const u64* __restrict__ gA, const u64* __restrict__ gB,
                  const int* __restrict__ flags,
                  float* __restrict__ partial) {
    int nRan = 1 + (flags[0] ? 1 : 0) + (flags[1] ? 1 : 0) + (flags[2] ? 1 : 0);
    const u64* dilb = (nRan & 1) ? gA : gB;    // dilated mask location

    const int b = blockIdx.x >> 6;       // 64 blocks per image
    const int chunk = blockIdx.x & 63;   // 1024 float4s per block
    const int tid = threadIdx.x;
    const int lane = tid & 63;
    const int wv = tid >> 6;
    const float4* x4 = (const float4*)(x + (size_t)b * NPIX);
    const u64* m = dilb + (size_t)b * WORDS_IMG;

    float sum = 0.0f;
    #pragma unroll
    for (int k = 0; k < 4; ++k) {
        int q = (chunk << 10) + (k << 8) + tid;   // float4 index in image
        u64 word = m[q >> 4];                      // 16 threads share a word
        u32 bits = (u32)(word >> ((q & 15) << 2)) & 0xFu;
        float4 v = x4[q];
        sum = fmaf((float)(bits & 1u), v.x, sum);
        sum = fmaf((float)((bits >> 1) & 1u), v.y, sum);
        sum = fmaf((float)((bits >> 2) & 1u), v.z, sum);
        sum = fmaf((float)((bits >> 3) & 1u), v.w, sum);
    }
    for (int off = 32; off >= 1; off >>= 1) sum += __shfl_down(sum, off, 64);
    __shared__ float s_red[4];
    if (lane == 0) s_red[wv] = sum;
    __syncthreads();
    if (tid == 0) partial[blockIdx.x] = (s_red[0] + s_red[1]) + (s_red[2] + s_red[3]);
}

// --------------- final: recall per image, mean, negate ----------------------
__global__ __launch_bounds__(64)
void final_kernel(const float* __restrict__ partial,
                  const int* __restrict__ gt,
                  float* __restrict__ out) {
    __shared__ float rec[32];
    int t = threadIdx.x;
    if (t < 32) {
        float inter = 0.0f;
        for (int j = 0; j < 64; ++j) inter += partial[t * 64 + j];
        rec[t] = (inter + 1.0f) / ((float)gt[t] + 1.0f);
    }
    __syncthreads();
    if (t == 0) {
        float s = 0.0f;
        for (int i = 0; i < 32; ++i) s += rec[i];
        out[0] = -(s / 32.0f);
    }
}

extern "C" void kernel_launch(void* const* d_in, const int* in_sizes, int n_in,
                              void* d_out, int out_size, void* d_ws, size_t ws_size,
                              hipStream_t stream) {
    const float* x = (const float*)d_in[0];
    const int*   y = (const int*)d_in[1];
    float* out = (float*)d_out;

    char* ws = (char*)d_ws;
    u64* gA = (u64*)ws;
    u64* gB = (u64*)(ws + (size_t)BATCH * WORDS_IMG * 8);
    int* flags = (int*)(ws + 2 * (size_t)BATCH * WORDS_IMG * 8);
    int* gt = flags + NPHASE;
    float* partial = (float*)(gt + BATCH);

    pack_kernel<<<512, 256, 0, stream>>>(y, gA, flags, gt);
    for (int p = 0; p < NPHASE; ++p) {
        const u64* src = (p & 1) ? gB : gA;
        u64* dst = (p & 1) ? gA : gB;
        strip_iter<<<BATCH * NSTRIP, 512, 0, stream>>>(src, dst, flags, p);
    }
    fallback_kernel<<<BATCH, 512, 0, stream>>>(gA, flags);
    dilate_gt_kernel<<<BATCH * NSTRIP, 512, 0, stream>>>(gA, gB, flags, gt);
    inter_kernel<<<BATCH * 64, 256, 0, stream>>>(x, gA, gB, flags, partial);
    final_kernel<<<1, 64, 0, stream>>>(partial, gt, out);
}